// Round 2
// baseline (766.019 us; speedup 1.0000x reference)
//
#include <hip/hip_runtime.h>
#include <cstdint>
#include <cstddef>

typedef unsigned short u16;
using half8 = __attribute__((ext_vector_type(8))) _Float16;
using f32x4 = __attribute__((ext_vector_type(4))) float;

#define B_    16
#define C_    256
#define H_    128
#define W_    128
#define C4_   64
#define COUT_ 256
#define HW_   (H_ * W_)

// LDS row strides (elements). All row strides are multiples of 8 elems (16 B)
// so ds_read_b128 fragment reads stay 16-B aligned.
#define LDS_S1    264   // kernel1 slab [w][c]: 256 + 8 pad
#define QK_S      72    // kernel2 Q/K [h][d]: 64 + 8 pad (bank step 36%32=4 -> 2-way free)
#define VT_S      136   // kernel2 V^T [c][g]: 128 + 8 pad
#define P_S       136   // kernel2 P   [h][g]: 128 + 8 pad

__device__ __forceinline__ u16 f16_rn(float f) {
  _Float16 h = (_Float16)f;   // RN
  return __builtin_bit_cast(u16, h);
}

// ---------------------------------------------------------------------------
// Kernel 1: Q/K/V 1x1-conv projections (fp16 operands, fp32 accum).
// Block = (b, h). Stages input slab [C][W] transposed to fp16 LDS [w][c],
// then out[w][dout] = sum_c slab[w][c] * W[dout][c] + bias via MFMA.
// ---------------------------------------------------------------------------
__device__ __forceinline__ void proj64(const u16* __restrict__ ldsT,
                                       const float* __restrict__ Wm,
                                       const float* __restrict__ bm,
                                       u16* __restrict__ dst,
                                       int b, int h, int wv, int col, int lg) {
  f32x4 zero = {0.f, 0.f, 0.f, 0.f};
  f32x4 acc[8];
#pragma unroll
  for (int i = 0; i < 8; ++i) acc[i] = zero;
#pragma unroll
  for (int ks = 0; ks < 8; ++ks) {
    const float* wp = Wm + (size_t)(wv * 16 + col) * C_ + ks * 32 + lg * 8;
    half8 bfr;
#pragma unroll
    for (int i = 0; i < 8; ++i) bfr[i] = (_Float16)wp[i];
#pragma unroll
    for (int wt = 0; wt < 8; ++wt) {
      const half8 afr = *reinterpret_cast<const half8*>(
          &ldsT[(wt * 16 + col) * LDS_S1 + ks * 32 + lg * 8]);
      acc[wt] = __builtin_amdgcn_mfma_f32_16x16x32_f16(afr, bfr, acc[wt], 0, 0, 0);
    }
  }
  const float bias = bm[wv * 16 + col];
#pragma unroll
  for (int wt = 0; wt < 8; ++wt)
#pragma unroll
    for (int r = 0; r < 4; ++r) {
      int w = wt * 16 + lg * 4 + r;
      dst[(((size_t)b * W_ + w) * H_ + h) * C4_ + wv * 16 + col] =
          f16_rn(acc[wt][r] + bias);
    }
}

__global__ void __launch_bounds__(256) qkv_kernel(
    const float* __restrict__ flow, const float* __restrict__ de_out,
    const float* __restrict__ Wq, const float* __restrict__ bq,
    const float* __restrict__ Wk, const float* __restrict__ bk,
    const float* __restrict__ Wv, const float* __restrict__ bv,
    u16* __restrict__ Qws, u16* __restrict__ Kws, u16* __restrict__ Vws) {
  __shared__ __align__(16) u16 ldsT[128 * LDS_S1];
  const int t    = threadIdx.x;
  const int bid  = blockIdx.x;
  const int b    = bid >> 7;
  const int h    = bid & 127;
  const int lane = t & 63;
  const int wv   = t >> 6;
  const int col  = lane & 15;
  const int lg   = lane >> 4;
  const int wloc = t & 127;
  const int coff = t >> 7;

  // ---- stage flow slab: ldsT[w][c] = f16(flow[b,c,h,w]) ----
  {
    const float* src = flow + (size_t)b * C_ * HW_ + (size_t)h * W_;
    for (int i = 0; i < 128; ++i) {
      int c = i * 2 + coff;
      ldsT[wloc * LDS_S1 + c] = f16_rn(src[(size_t)c * HW_ + wloc]);
    }
  }
  __syncthreads();

  // ---- K: wave wv owns d-tile wv ----
  proj64(ldsT, Wk, bk, Kws, b, h, wv, col, lg);

  // ---- V: wave wv owns c-tiles [4wv, 4wv+4) ----
  {
    f32x4 zero = {0.f, 0.f, 0.f, 0.f};
    f32x4 acc[4][8];
#pragma unroll
    for (int j = 0; j < 4; ++j)
#pragma unroll
      for (int i = 0; i < 8; ++i) acc[j][i] = zero;
#pragma unroll
    for (int ks = 0; ks < 8; ++ks) {
      half8 bfr[4];
#pragma unroll
      for (int j = 0; j < 4; ++j) {
        const float* wp =
            Wv + (size_t)((wv * 4 + j) * 16 + col) * C_ + ks * 32 + lg * 8;
#pragma unroll
        for (int i = 0; i < 8; ++i) bfr[j][i] = (_Float16)wp[i];
      }
#pragma unroll
      for (int wt = 0; wt < 8; ++wt) {
        const half8 afr = *reinterpret_cast<const half8*>(
            &ldsT[(wt * 16 + col) * LDS_S1 + ks * 32 + lg * 8]);
#pragma unroll
        for (int j = 0; j < 4; ++j)
          acc[j][wt] =
              __builtin_amdgcn_mfma_f32_16x16x32_f16(afr, bfr[j], acc[j][wt], 0, 0, 0);
      }
    }
#pragma unroll
    for (int j = 0; j < 4; ++j) {
      const int co = (wv * 4 + j) * 16 + col;
      const float bias = bv[co];
#pragma unroll
      for (int wt = 0; wt < 8; ++wt)
#pragma unroll
        for (int r = 0; r < 4; ++r) {
          int w = wt * 16 + lg * 4 + r;
          Vws[(((size_t)b * W_ + w) * H_ + h) * COUT_ + co] =
              f16_rn(acc[j][wt][r] + bias);
        }
    }
  }
  __syncthreads();

  // ---- stage de_out slab ----
  {
    const float* src = de_out + (size_t)b * C_ * HW_ + (size_t)h * W_;
    for (int i = 0; i < 128; ++i) {
      int c = i * 2 + coff;
      ldsT[wloc * LDS_S1 + c] = f16_rn(src[(size_t)c * HW_ + wloc]);
    }
  }
  __syncthreads();

  // ---- Q ----
  proj64(ldsT, Wq, bq, Qws, b, h, wv, col, lg);
}

// ---------------------------------------------------------------------------
// Kernel 2: per-(b,w)-column attention.
// Block = one column (XCD-chunk swizzled: each XCD gets 2 full b's so the
// scattered fp32 output stores merge to full lines inside one XCD's L2).
// E = Q K^T (MFMA), wave-local softmax over g, O = P V (MFMA).
// ---------------------------------------------------------------------------
__global__ void __launch_bounds__(256) attn_kernel(
    const u16* __restrict__ Qws, const u16* __restrict__ Kws,
    const u16* __restrict__ Vws, float* __restrict__ out) {
  __shared__ __align__(16) u16 ldsQ[128 * QK_S];
  __shared__ __align__(16) u16 ldsK[128 * QK_S];
  __shared__ __align__(16) u16 ldsVT[256 * VT_S];
  __shared__ __align__(16) u16 ldsP[4][32 * P_S];

  const int t   = threadIdx.x;
  const int bid = blockIdx.x;
  const int sw  = (bid & 7) * 256 + (bid >> 3);  // bijective (2048 % 8 == 0)
  const int b   = sw >> 7;
  const int w   = sw & 127;
  const int lane = t & 63;
  const int wv   = t >> 6;
  const int col  = lane & 15;
  const int lg   = lane >> 4;

  const u16* qc = Qws + ((size_t)b * W_ + w) * H_ * C4_;
  const u16* kc = Kws + ((size_t)b * W_ + w) * H_ * C4_;
  const u16* vc = Vws + ((size_t)b * W_ + w) * H_ * COUT_;

  // stage Q, K: [h][d] (contiguous per column in ws)
  for (int i = 0; i < 32; ++i) {
    int flat = i * 256 + t;
    int hh = flat >> 6, d = flat & 63;
    ldsQ[hh * QK_S + d] = qc[flat];
    ldsK[hh * QK_S + d] = kc[flat];
  }
  // stage V transposed: ldsVT[c][g]
  for (int i = 0; i < 128; ++i) {
    int flat = i * 256 + t;
    int g = flat >> 8, c = flat & 255;
    ldsVT[c * VT_S + g] = vc[flat];
  }
  __syncthreads();

  // ---- E = Q K^T for rows [wv*32, wv*32+32), all 128 g ----
  f32x4 zero = {0.f, 0.f, 0.f, 0.f};
  f32x4 e[2][8];
#pragma unroll
  for (int ht = 0; ht < 2; ++ht)
#pragma unroll
    for (int gt = 0; gt < 8; ++gt) e[ht][gt] = zero;

#pragma unroll
  for (int ks = 0; ks < 2; ++ks) {
    half8 aq[2];
#pragma unroll
    for (int ht = 0; ht < 2; ++ht)
      aq[ht] = *reinterpret_cast<const half8*>(
          &ldsQ[(wv * 32 + ht * 16 + col) * QK_S + ks * 32 + lg * 8]);
#pragma unroll
    for (int gt = 0; gt < 8; ++gt) {
      const half8 bk_ = *reinterpret_cast<const half8*>(
          &ldsK[(gt * 16 + col) * QK_S + ks * 32 + lg * 8]);
#pragma unroll
      for (int ht = 0; ht < 2; ++ht)
        e[ht][gt] = __builtin_amdgcn_mfma_f32_16x16x32_f16(aq[ht], bk_, e[ht][gt], 0, 0, 0);
    }
  }

  // ---- softmax over g; row (lg*4+r) lives in the 16 lanes of group lg ----
#pragma unroll
  for (int ht = 0; ht < 2; ++ht)
#pragma unroll
    for (int r = 0; r < 4; ++r) {
      float m = -1e30f;
#pragma unroll
      for (int gt = 0; gt < 8; ++gt) m = fmaxf(m, e[ht][gt][r]);
#pragma unroll
      for (int off = 1; off < 16; off <<= 1) m = fmaxf(m, __shfl_xor(m, off));
      float s = 0.f;
#pragma unroll
      for (int gt = 0; gt < 8; ++gt) {
        float p = __expf(e[ht][gt][r] - m);
        e[ht][gt][r] = p;
        s += p;
      }
#pragma unroll
      for (int off = 1; off < 16; off <<= 1) s += __shfl_xor(s, off);
      const float inv = 1.f / s;
      const int hh = ht * 16 + lg * 4 + r;  // row within wave's 32
#pragma unroll
      for (int gt = 0; gt < 8; ++gt)
        ldsP[wv][hh * P_S + gt * 16 + col] = f16_rn(e[ht][gt][r] * inv);
    }
  // ldsP is wave-private: no barrier needed (wave-synchronous + lgkmcnt).

  // ---- O = P V : rows [wv*32,+32) x 256 c ----
  f32x4 o[2][16];
#pragma unroll
  for (int ht = 0; ht < 2; ++ht)
#pragma unroll
    for (int ct = 0; ct < 16; ++ct) o[ht][ct] = zero;

#pragma unroll
  for (int ks = 0; ks < 4; ++ks) {
    half8 ap[2];
#pragma unroll
    for (int ht = 0; ht < 2; ++ht)
      ap[ht] = *reinterpret_cast<const half8*>(
          &ldsP[wv][(ht * 16 + col) * P_S + ks * 32 + lg * 8]);
#pragma unroll
    for (int ct = 0; ct < 16; ++ct) {
      const half8 bv_ = *reinterpret_cast<const half8*>(
          &ldsVT[(ct * 16 + col) * VT_S + ks * 32 + lg * 8]);
#pragma unroll
      for (int ht = 0; ht < 2; ++ht)
        o[ht][ct] = __builtin_amdgcn_mfma_f32_16x16x32_f16(ap[ht], bv_, o[ht][ct], 0, 0, 0);
    }
  }

  // ---- epilogue: out[b, c, h, w] (fp32) ----
  float* outp = out + (size_t)b * COUT_ * HW_ + w;
#pragma unroll
  for (int ht = 0; ht < 2; ++ht)
#pragma unroll
    for (int ct = 0; ct < 16; ++ct)
#pragma unroll
      for (int r = 0; r < 4; ++r) {
        int hrow = wv * 32 + ht * 16 + lg * 4 + r;
        int c = ct * 16 + col;
        outp[((size_t)c * H_ + hrow) * W_] = o[ht][ct][r];
      }
}

extern "C" void kernel_launch(void* const* d_in, const int* in_sizes, int n_in,
                              void* d_out, int out_size, void* d_ws, size_t ws_size,
                              hipStream_t stream) {
  const float* flow   = (const float*)d_in[0];
  const float* de_out = (const float*)d_in[1];
  const float* Wq = (const float*)d_in[2];
  const float* bq = (const float*)d_in[3];
  const float* Wk = (const float*)d_in[4];
  const float* bk = (const float*)d_in[5];
  const float* Wv = (const float*)d_in[6];
  const float* bv = (const float*)d_in[7];
  float* out = (float*)d_out;

  u16* Qws = (u16*)d_ws;                                   // B*W*H*C4 fp16
  u16* Kws = Qws + (size_t)B_ * W_ * H_ * C4_;             // B*W*H*C4 fp16
  u16* Vws = Kws + (size_t)B_ * W_ * H_ * C4_;             // B*W*H*COUT fp16
  // total ws use: 201,326,592 bytes

  qkv_kernel<<<B_ * H_, 256, 0, stream>>>(flow, de_out, Wq, bq, Wk, bk, Wv, bv,
                                          Qws, Kws, Vws);
  attn_kernel<<<B_ * W_, 256, 0, stream>>>(Qws, Kws, Vws, out);
}